// Round 1
// baseline (977.416 us; speedup 1.0000x reference)
//
#include <hip/hip_runtime.h>
#include <hip/hip_bf16.h>
#include <math.h>

#define N_NODES 50000
#define E_EDGES 262144
#define D_FEAT  128
#define H_HID   256
#define NEXP    4

// ws layout:
//   [0..15]              float probsum[4]
//   [16..31]             unsigned count[4]
//   [32 .. 32+16*E)      int lists[4][E]
//   [32+16*E .. +4*E)    float pval[E]

// ---------------------------------------------------------------------------
// Phase 1: gate logits (fp64 accum), softmax, argmax, compaction, prob sums
// ---------------------------------------------------------------------------
__global__ __launch_bounds__(256) void gate_kernel(
    const float* __restrict__ z, const int* __restrict__ u, const int* __restrict__ v,
    const float* __restrict__ gw, const float* __restrict__ gb,
    float* __restrict__ probsum, unsigned* __restrict__ gcount,
    int* __restrict__ lists, float* __restrict__ pval)
{
    int tid  = threadIdx.x;
    int lane = tid & 63;
    int e    = blockIdx.x * 256 + tid;

    int ue = u[e], ve = v[e];
    const float* zu = z + (long)ue * D_FEAT;
    const float* zv = z + (long)ve * D_FEAT;

    double l0 = (double)gb[0], l1 = (double)gb[1], l2 = (double)gb[2], l3 = (double)gb[3];

    for (int d = 0; d < D_FEAT; ++d) {
        float a  = zu[d];
        float b  = zv[d];
        float ad = fabsf(a - b);
        float m  = a * b;
        // gate_w rows: d (z_u), 128+d (z_v), 256+d (diff), 384+d (mul); 4 cols each
        const float4 g0 = *(const float4*)(gw + 4 * d);
        const float4 g1 = *(const float4*)(gw + 4 * (128 + d));
        const float4 g2 = *(const float4*)(gw + 4 * (256 + d));
        const float4 g3 = *(const float4*)(gw + 4 * (384 + d));
        l0 += (double)a * (double)g0.x + (double)b * (double)g1.x
            + (double)ad * (double)g2.x + (double)m * (double)g3.x;
        l1 += (double)a * (double)g0.y + (double)b * (double)g1.y
            + (double)ad * (double)g2.y + (double)m * (double)g3.y;
        l2 += (double)a * (double)g0.z + (double)b * (double)g1.z
            + (double)ad * (double)g2.z + (double)m * (double)g3.z;
        l3 += (double)a * (double)g0.w + (double)b * (double)g1.w
            + (double)ad * (double)g2.w + (double)m * (double)g3.w;
    }

    // softmax in double, then round probs to fp32 (matches np fp32 prob compare)
    double mx = fmax(fmax(l0, l1), fmax(l2, l3));
    double e0 = exp(l0 - mx), e1 = exp(l1 - mx), e2 = exp(l2 - mx), e3 = exp(l3 - mx);
    double s  = e0 + e1 + e2 + e3;
    float p[4];
    p[0] = (float)(e0 / s); p[1] = (float)(e1 / s);
    p[2] = (float)(e2 / s); p[3] = (float)(e3 / s);

    int   sel  = 0;
    float best = p[0];
    #pragma unroll
    for (int k = 1; k < 4; ++k) {            // strict > keeps first index on ties (top_k semantics)
        if (p[k] > best) { best = p[k]; sel = k; }
    }

    __shared__ float s_ps[4];
    __shared__ int   s_cnt[4];
    __shared__ int   s_base[4];
    if (tid < 4) { s_ps[tid] = 0.0f; s_cnt[tid] = 0; }
    __syncthreads();

    // wave-reduce the 4 probs for aux_loss
    float q0 = p[0], q1 = p[1], q2 = p[2], q3 = p[3];
    #pragma unroll
    for (int off = 32; off > 0; off >>= 1) {
        q0 += __shfl_down(q0, off);
        q1 += __shfl_down(q1, off);
        q2 += __shfl_down(q2, off);
        q3 += __shfl_down(q3, off);
    }
    if (lane == 0) {
        atomicAdd(&s_ps[0], q0); atomicAdd(&s_ps[1], q1);
        atomicAdd(&s_ps[2], q2); atomicAdd(&s_ps[3], q3);
    }

    // wave-aggregated compaction ranks
    unsigned long long lt = (lane == 0) ? 0ull : ((~0ull) >> (64 - lane));
    int mywb = 0, myrank = 0;
    #pragma unroll
    for (int k = 0; k < 4; ++k) {
        unsigned long long mask = __ballot(sel == k);
        if (mask) {
            int leader = (int)__ffsll((unsigned long long)mask) - 1;
            int wb = 0;
            if (lane == leader) wb = atomicAdd(&s_cnt[k], (int)__popcll(mask));
            wb = __shfl(wb, leader);
            if (sel == k) { mywb = wb; myrank = (int)__popcll(mask & lt); }
        }
    }
    __syncthreads();

    if (tid < 4) {
        s_base[tid] = (int)atomicAdd(&gcount[tid], (unsigned)s_cnt[tid]);
        atomicAdd(&probsum[tid], s_ps[tid]);
    }
    __syncthreads();

    int pos = s_base[sel] + mywb + myrank;
    lists[sel * E_EDGES + pos] = e;
    pval[e] = best;
}

// ---------------------------------------------------------------------------
// Phase 2: selected-expert MLP.  blockIdx.y = expert, 16 edges x 256 hidden.
// ---------------------------------------------------------------------------
__global__ __launch_bounds__(256) void expert_kernel(
    const float* __restrict__ z, const int* __restrict__ u, const int* __restrict__ v,
    const float* __restrict__ cw1, const float* __restrict__ cb1,
    const float* __restrict__ cw2, const float* __restrict__ cb2,
    const float* __restrict__ dw1, const float* __restrict__ db1,
    const float* __restrict__ dw2, const float* __restrict__ db2,
    const float* __restrict__ mw1, const float* __restrict__ mb1,
    const float* __restrict__ mw2, const float* __restrict__ mb2,
    const float* __restrict__ aw1, const float* __restrict__ ab1,
    const float* __restrict__ aw2, const float* __restrict__ ab2,
    const unsigned* __restrict__ gcount, const int* __restrict__ lists,
    const float* __restrict__ pval, float* __restrict__ out)
{
    int ex = blockIdx.y;
    const float *w1, *b1, *w2, *b2;
    int F;
    if (ex == 0)      { w1 = cw1; b1 = cb1; w2 = cw2; b2 = cb2; F = 256; }
    else if (ex == 1) { w1 = dw1; b1 = db1; w2 = dw2; b2 = db2; F = 128; }
    else if (ex == 2) { w1 = mw1; b1 = mb1; w2 = mw2; b2 = mb2; F = 128; }
    else              { w1 = aw1; b1 = ab1; w2 = aw2; b2 = ab2; F = 512; }

    unsigned cnt  = gcount[ex];
    unsigned tile = blockIdx.x * 16u;
    if (tile >= cnt) return;
    int nm = (int)min(16u, cnt - tile);

    __shared__ float feat_s[16][64];
    __shared__ int   s_e[16], s_u[16], s_v[16];
    __shared__ float s_pv[16];
    __shared__ float red[4][16];

    int tid = threadIdx.x;
    if (tid < 16) {
        int m = tid;
        int src = (m < nm) ? (int)(tile + m) : (int)tile;   // clamp tail to a valid edge
        int e = lists[ex * E_EDGES + src];
        s_e[m] = e; s_u[m] = u[e]; s_v[m] = v[e]; s_pv[m] = pval[e];
    }
    __syncthreads();

    float acc[16];
    #pragma unroll
    for (int m = 0; m < 16; ++m) acc[m] = 0.0f;

    for (int f0 = 0; f0 < F; f0 += 64) {
        if (f0 > 0) __syncthreads();   // previous chunk's reads done before overwrite
        #pragma unroll
        for (int r = 0; r < 4; ++r) {
            int it = tid + 256 * r;
            int m  = it >> 6;
            int f  = it & 63;
            int fg = f0 + f;
            const float* zu = z + (long)s_u[m] * D_FEAT;
            const float* zv = z + (long)s_v[m] * D_FEAT;
            float val;
            if (ex == 0) {
                val = (fg < 128) ? zu[fg] : zv[fg - 128];
            } else if (ex == 1) {
                val = fabsf(zu[fg] - zv[fg]);
            } else if (ex == 2) {
                val = zu[fg] * zv[fg];
            } else {
                if (fg < 128)      val = zu[fg];
                else if (fg < 256) val = zv[fg - 128];
                else if (fg < 384) val = fabsf(zu[fg - 256] - zv[fg - 256]);
                else               val = zu[fg - 384] * zv[fg - 384];
            }
            feat_s[m][f] = val;
        }
        __syncthreads();

        for (int f4 = 0; f4 < 64; f4 += 4) {
            float wa = w1[(f0 + f4 + 0) * H_HID + tid];
            float wb = w1[(f0 + f4 + 1) * H_HID + tid];
            float wc = w1[(f0 + f4 + 2) * H_HID + tid];
            float wd = w1[(f0 + f4 + 3) * H_HID + tid];
            #pragma unroll
            for (int m = 0; m < 16; ++m) {
                float4 fv = *reinterpret_cast<const float4*>(&feat_s[m][f4]);
                acc[m] = fmaf(fv.x, wa, acc[m]);
                acc[m] = fmaf(fv.y, wb, acc[m]);
                acc[m] = fmaf(fv.z, wc, acc[m]);
                acc[m] = fmaf(fv.w, wd, acc[m]);
            }
        }
    }

    // second layer: hidden = relu(acc + b1[h]); contrib = hidden * w2[h]; sum over h
    float bias = b1[tid];
    float wout = w2[tid];
    int wave = tid >> 6, lane = tid & 63;
    #pragma unroll
    for (int m = 0; m < 16; ++m) {
        float h = acc[m] + bias;
        h = fmaxf(h, 0.0f);
        float c = h * wout;
        #pragma unroll
        for (int off = 32; off > 0; off >>= 1) c += __shfl_down(c, off);
        if (lane == 0) red[wave][m] = c;
    }
    __syncthreads();
    if (tid < 16) {
        int m = tid;
        if (m < nm) {
            float sc = red[0][m] + red[1][m] + red[2][m] + red[3][m] + b2[0];
            out[s_e[m]] = s_pv[m] * sc;
        }
    }
}

// ---------------------------------------------------------------------------
// Phase 3: aux loss
// ---------------------------------------------------------------------------
__global__ void aux_kernel(const float* __restrict__ probsum, float* __restrict__ out)
{
    if (threadIdx.x == 0 && blockIdx.x == 0) {
        float a = 0.0f;
        #pragma unroll
        for (int k = 0; k < 4; ++k) {
            float mean = probsum[k] * (1.0f / (float)E_EDGES);
            a += mean * mean;
        }
        out[E_EDGES] = a * (float)NEXP;
    }
}

extern "C" void kernel_launch(void* const* d_in, const int* in_sizes, int n_in,
                              void* d_out, int out_size, void* d_ws, size_t ws_size,
                              hipStream_t stream)
{
    const float* z   = (const float*)d_in[0];
    const int*   u   = (const int*)d_in[1];
    const int*   v   = (const int*)d_in[2];
    const float* gw  = (const float*)d_in[3];
    const float* gb  = (const float*)d_in[4];
    const float* cw1 = (const float*)d_in[5];
    const float* cb1 = (const float*)d_in[6];
    const float* cw2 = (const float*)d_in[7];
    const float* cb2 = (const float*)d_in[8];
    const float* dw1 = (const float*)d_in[9];
    const float* db1 = (const float*)d_in[10];
    const float* dw2 = (const float*)d_in[11];
    const float* db2 = (const float*)d_in[12];
    const float* mw1 = (const float*)d_in[13];
    const float* mb1 = (const float*)d_in[14];
    const float* mw2 = (const float*)d_in[15];
    const float* mb2 = (const float*)d_in[16];
    const float* aw1 = (const float*)d_in[17];
    const float* ab1 = (const float*)d_in[18];
    const float* aw2 = (const float*)d_in[19];
    const float* ab2 = (const float*)d_in[20];

    float* out = (float*)d_out;
    char*  ws  = (char*)d_ws;

    float*    probsum = (float*)ws;                            // 4 floats
    unsigned* gcount  = (unsigned*)(ws + 16);                  // 4 uints
    int*      lists   = (int*)(ws + 32);                       // 4*E ints
    float*    pval    = (float*)(ws + 32 + 16ll * E_EDGES);    // E floats

    hipMemsetAsync(d_ws, 0, 32, stream);

    gate_kernel<<<E_EDGES / 256, 256, 0, stream>>>(z, u, v, gw, gb,
                                                   probsum, gcount, lists, pval);

    aux_kernel<<<1, 64, 0, stream>>>(probsum, out);

    dim3 g2(E_EDGES / 16, 4);
    expert_kernel<<<g2, 256, 0, stream>>>(z, u, v,
                                          cw1, cb1, cw2, cb2,
                                          dw1, db1, dw2, db2,
                                          mw1, mb1, mw2, mb2,
                                          aw1, ab1, aw2, ab2,
                                          gcount, lists, pval, out);
}

// Round 2
// 365.070 us; speedup vs baseline: 2.6773x; 2.6773x over previous
//
#include <hip/hip_runtime.h>
#include <hip/hip_bf16.h>
#include <math.h>

#define N_NODES 50000
#define E_EDGES 262144
#define D_FEAT  128
#define H_HID   256
#define NEXP    4

typedef __attribute__((ext_vector_type(8))) short  short8;
typedef __attribute__((ext_vector_type(4))) float  floatx4;

// ws layout:
//   [0..15]                      float probsum[4]
//   [16..31]                     unsigned count[4]
//   [32 .. 32+16*E)              int lists[4][E]
//   [+4*E)                       float pval[E]
//   [+512K)                      ushort w1b[262144]  (bf16, B-fragment-linear)
#define W1B_OFF0 0
#define W1B_OFF1 65536      // 256*256
#define W1B_OFF2 98304      // +128*256
#define W1B_OFF3 131072     // +128*256
#define W1B_TOT  262144

__device__ __forceinline__ unsigned short f2bf(float f) {
    __hip_bfloat16 h = __float2bfloat16(f);       // RNE
    return *reinterpret_cast<unsigned short*>(&h);
}

// ---------------------------------------------------------------------------
// Phase 0: convert the four W1 matrices to bf16 in B-fragment-linear layout:
//   w1b[exoff + ((k>>3)*256 + n)*8 + (k&7)] = bf16(w1[k*256+n])
// so a lane's 8-element B fragment (k = 8g..8g+7 fixed n) is one 16B load.
// ---------------------------------------------------------------------------
__global__ __launch_bounds__(256) void conv_kernel(
    const float* __restrict__ cw1, const float* __restrict__ dw1,
    const float* __restrict__ mw1, const float* __restrict__ aw1,
    unsigned short* __restrict__ w1b)
{
    int r = blockIdx.x;          // 0..1023 global K row
    int n = threadIdx.x;         // 0..255
    const float* src; int k, off;
    if (r < 256)      { src = cw1; k = r;       off = W1B_OFF0; }
    else if (r < 384) { src = dw1; k = r - 256; off = W1B_OFF1; }
    else if (r < 512) { src = mw1; k = r - 384; off = W1B_OFF2; }
    else              { src = aw1; k = r - 512; off = W1B_OFF3; }
    w1b[off + (((k >> 3) * 256 + n) << 3) + (k & 7)] = f2bf(src[k * 256 + n]);
}

// ---------------------------------------------------------------------------
// Phase 1: gate logits (fp64 accum), softmax, argmax, compaction, prob sums
// ---------------------------------------------------------------------------
__global__ __launch_bounds__(256) void gate_kernel(
    const float* __restrict__ z, const int* __restrict__ u, const int* __restrict__ v,
    const float* __restrict__ gw, const float* __restrict__ gb,
    float* __restrict__ probsum, unsigned* __restrict__ gcount,
    int* __restrict__ lists, float* __restrict__ pval)
{
    int tid  = threadIdx.x;
    int lane = tid & 63;
    int e    = blockIdx.x * 256 + tid;

    int ue = u[e], ve = v[e];
    const float* zu = z + (long)ue * D_FEAT;
    const float* zv = z + (long)ve * D_FEAT;

    double l0 = (double)gb[0], l1 = (double)gb[1], l2 = (double)gb[2], l3 = (double)gb[3];

    for (int d = 0; d < D_FEAT; ++d) {
        float a  = zu[d];
        float b  = zv[d];
        float ad = fabsf(a - b);
        float m  = a * b;
        const float4 g0 = *(const float4*)(gw + 4 * d);
        const float4 g1 = *(const float4*)(gw + 4 * (128 + d));
        const float4 g2 = *(const float4*)(gw + 4 * (256 + d));
        const float4 g3 = *(const float4*)(gw + 4 * (384 + d));
        l0 += (double)a * (double)g0.x + (double)b * (double)g1.x
            + (double)ad * (double)g2.x + (double)m * (double)g3.x;
        l1 += (double)a * (double)g0.y + (double)b * (double)g1.y
            + (double)ad * (double)g2.y + (double)m * (double)g3.y;
        l2 += (double)a * (double)g0.z + (double)b * (double)g1.z
            + (double)ad * (double)g2.z + (double)m * (double)g3.z;
        l3 += (double)a * (double)g0.w + (double)b * (double)g1.w
            + (double)ad * (double)g2.w + (double)m * (double)g3.w;
    }

    double mx = fmax(fmax(l0, l1), fmax(l2, l3));
    double e0 = exp(l0 - mx), e1 = exp(l1 - mx), e2 = exp(l2 - mx), e3 = exp(l3 - mx);
    double s  = e0 + e1 + e2 + e3;
    float p[4];
    p[0] = (float)(e0 / s); p[1] = (float)(e1 / s);
    p[2] = (float)(e2 / s); p[3] = (float)(e3 / s);

    int   sel  = 0;
    float best = p[0];
    #pragma unroll
    for (int k = 1; k < 4; ++k) {
        if (p[k] > best) { best = p[k]; sel = k; }
    }

    __shared__ float s_ps[4];
    __shared__ int   s_cnt[4];
    __shared__ int   s_base[4];
    if (tid < 4) { s_ps[tid] = 0.0f; s_cnt[tid] = 0; }
    __syncthreads();

    float q0 = p[0], q1 = p[1], q2 = p[2], q3 = p[3];
    #pragma unroll
    for (int off = 32; off > 0; off >>= 1) {
        q0 += __shfl_down(q0, off);
        q1 += __shfl_down(q1, off);
        q2 += __shfl_down(q2, off);
        q3 += __shfl_down(q3, off);
    }
    if (lane == 0) {
        atomicAdd(&s_ps[0], q0); atomicAdd(&s_ps[1], q1);
        atomicAdd(&s_ps[2], q2); atomicAdd(&s_ps[3], q3);
    }

    unsigned long long lt = (lane == 0) ? 0ull : ((~0ull) >> (64 - lane));
    int mywb = 0, myrank = 0;
    #pragma unroll
    for (int k = 0; k < 4; ++k) {
        unsigned long long mask = __ballot(sel == k);
        if (mask) {
            int leader = (int)__ffsll((unsigned long long)mask) - 1;
            int wb = 0;
            if (lane == leader) wb = atomicAdd(&s_cnt[k], (int)__popcll(mask));
            wb = __shfl(wb, leader);
            if (sel == k) { mywb = wb; myrank = (int)__popcll(mask & lt); }
        }
    }
    __syncthreads();

    if (tid < 4) {
        s_base[tid] = (int)atomicAdd(&gcount[tid], (unsigned)s_cnt[tid]);
        atomicAdd(&probsum[tid], s_ps[tid]);
    }
    __syncthreads();

    int pos = s_base[sel] + mywb + myrank;
    lists[sel * E_EDGES + pos] = e;
    pval[e] = best;
}

// ---------------------------------------------------------------------------
// Phase 2: selected-expert MLP via bf16 MFMA.
// Block = 256 threads = 4 waves; tile = 32 edges x 256 hidden.
// Wave w owns hidden cols [w*64, w*64+64): 2 M-tiles x 4 N-tiles of 16x16.
// K-loop: stage 32 edges x 32 features (bf16) in LDS, MFMA against w1b frags.
// ---------------------------------------------------------------------------
#define FPAD 40   // row stride (elems) for feat LDS: 80B rows keep b128 16B-aligned

__global__ __launch_bounds__(256) void expert_kernel(
    const float* __restrict__ z, const int* __restrict__ u, const int* __restrict__ v,
    const unsigned short* __restrict__ w1b,
    const float* __restrict__ cb1, const float* __restrict__ cw2, const float* __restrict__ cb2,
    const float* __restrict__ db1, const float* __restrict__ dw2, const float* __restrict__ db2,
    const float* __restrict__ mb1, const float* __restrict__ mw2, const float* __restrict__ mb2,
    const float* __restrict__ ab1, const float* __restrict__ aw2, const float* __restrict__ ab2,
    const unsigned* __restrict__ gcount, const int* __restrict__ lists,
    const float* __restrict__ pval, float* __restrict__ out)
{
    int ex = blockIdx.y;
    const float *b1, *w2, *b2;
    int F, w1off;
    if (ex == 0)      { b1 = cb1; w2 = cw2; b2 = cb2; F = 256; w1off = W1B_OFF0; }
    else if (ex == 1) { b1 = db1; w2 = dw2; b2 = db2; F = 128; w1off = W1B_OFF1; }
    else if (ex == 2) { b1 = mb1; w2 = mw2; b2 = mb2; F = 128; w1off = W1B_OFF2; }
    else              { b1 = ab1; w2 = aw2; b2 = ab2; F = 512; w1off = W1B_OFF3; }

    unsigned cnt  = gcount[ex];
    unsigned tile = blockIdx.x * 32u;
    if (tile >= cnt) return;
    int nm = (int)min(32u, cnt - tile);

    __shared__ unsigned short featA[32 * FPAD];
    __shared__ int   s_e[32], s_u[32], s_v[32];
    __shared__ float s_pv[32];
    __shared__ float red[4][32];

    int tid  = threadIdx.x;
    int wave = tid >> 6;
    int lane = tid & 63;
    int colA = lane & 15;
    int quad = lane >> 4;

    if (tid < 32) {
        int m = tid;
        int src = (m < nm) ? (int)(tile + m) : (int)tile;
        int e = lists[ex * E_EDGES + src];
        s_e[m] = e; s_u[m] = u[e]; s_v[m] = v[e]; s_pv[m] = pval[e];
    }
    __syncthreads();

    const short8* wB = (const short8*)(w1b + w1off);

    floatx4 acc[2][4];
    #pragma unroll
    for (int t = 0; t < 2; ++t)
        #pragma unroll
        for (int j = 0; j < 4; ++j)
            acc[t][j] = (floatx4)(0.0f);

    // feature-build indices: thread -> (edge m, 4 consecutive k)
    int fm = tid >> 3;
    int fk = (tid & 7) << 2;

    for (int f0 = 0; f0 < F; f0 += 32) {
        // issue B-fragment loads first (no LDS dependence -> overlaps build)
        int g = (f0 >> 3) + quad;
        int nb = wave * 64 + colA;
        short8 bf0 = wB[g * 256 + nb +  0];
        short8 bf1 = wB[g * 256 + nb + 16];
        short8 bf2 = wB[g * 256 + nb + 32];
        short8 bf3 = wB[g * 256 + nb + 48];

        // build 32x32 bf16 feature chunk
        {
            int fg = f0 + fk;
            const float* zu = z + (long)s_u[fm] * D_FEAT;
            const float* zv = z + (long)s_v[fm] * D_FEAT;
            float4 val;
            if (ex == 0) {
                val = (fg < 128) ? *(const float4*)(zu + fg)
                                 : *(const float4*)(zv + fg - 128);
            } else if (ex == 1) {
                float4 a = *(const float4*)(zu + fg);
                float4 b = *(const float4*)(zv + fg);
                val.x = fabsf(a.x - b.x); val.y = fabsf(a.y - b.y);
                val.z = fabsf(a.z - b.z); val.w = fabsf(a.w - b.w);
            } else if (ex == 2) {
                float4 a = *(const float4*)(zu + fg);
                float4 b = *(const float4*)(zv + fg);
                val.x = a.x * b.x; val.y = a.y * b.y;
                val.z = a.z * b.z; val.w = a.w * b.w;
            } else {
                if (fg < 128) {
                    val = *(const float4*)(zu + fg);
                } else if (fg < 256) {
                    val = *(const float4*)(zv + fg - 128);
                } else if (fg < 384) {
                    float4 a = *(const float4*)(zu + fg - 256);
                    float4 b = *(const float4*)(zv + fg - 256);
                    val.x = fabsf(a.x - b.x); val.y = fabsf(a.y - b.y);
                    val.z = fabsf(a.z - b.z); val.w = fabsf(a.w - b.w);
                } else {
                    float4 a = *(const float4*)(zu + fg - 384);
                    float4 b = *(const float4*)(zv + fg - 384);
                    val.x = a.x * b.x; val.y = a.y * b.y;
                    val.z = a.z * b.z; val.w = a.w * b.w;
                }
            }
            ushort4 pk;
            pk.x = f2bf(val.x); pk.y = f2bf(val.y);
            pk.z = f2bf(val.z); pk.w = f2bf(val.w);
            *(ushort4*)(&featA[fm * FPAD + fk]) = pk;
        }
        __syncthreads();

        short8 a0 = *(const short8*)(&featA[colA * FPAD + quad * 8]);
        short8 a1 = *(const short8*)(&featA[(16 + colA) * FPAD + quad * 8]);

        acc[0][0] = __builtin_amdgcn_mfma_f32_16x16x32_bf16(a0, bf0, acc[0][0], 0, 0, 0);
        acc[1][0] = __builtin_amdgcn_mfma_f32_16x16x32_bf16(a1, bf0, acc[1][0], 0, 0, 0);
        acc[0][1] = __builtin_amdgcn_mfma_f32_16x16x32_bf16(a0, bf1, acc[0][1], 0, 0, 0);
        acc[1][1] = __builtin_amdgcn_mfma_f32_16x16x32_bf16(a1, bf1, acc[1][1], 0, 0, 0);
        acc[0][2] = __builtin_amdgcn_mfma_f32_16x16x32_bf16(a0, bf2, acc[0][2], 0, 0, 0);
        acc[1][2] = __builtin_amdgcn_mfma_f32_16x16x32_bf16(a1, bf2, acc[1][2], 0, 0, 0);
        acc[0][3] = __builtin_amdgcn_mfma_f32_16x16x32_bf16(a0, bf3, acc[0][3], 0, 0, 0);
        acc[1][3] = __builtin_amdgcn_mfma_f32_16x16x32_bf16(a1, bf3, acc[1][3], 0, 0, 0);
        __syncthreads();
    }

    // epilogue: hidden = relu(acc + b1[h]); per-edge sum of hidden*w2[h]
    float b1v[4], w2v[4];
    #pragma unroll
    for (int j = 0; j < 4; ++j) {
        int h = wave * 64 + j * 16 + colA;
        b1v[j] = b1[h];
        w2v[j] = w2[h];
    }

    #pragma unroll
    for (int t = 0; t < 2; ++t) {
        #pragma unroll
        for (int r = 0; r < 4; ++r) {
            float s = 0.0f;
            #pragma unroll
            for (int j = 0; j < 4; ++j) {
                float h = acc[t][j][r] + b1v[j];
                s += fmaxf(h, 0.0f) * w2v[j];
            }
            s += __shfl_xor(s, 1);
            s += __shfl_xor(s, 2);
            s += __shfl_xor(s, 4);
            s += __shfl_xor(s, 8);
            if (colA == 0) {
                int m = 16 * t + quad * 4 + r;
                red[wave][m] = s;
            }
        }
    }
    __syncthreads();

    if (tid < 32) {
        int m = tid;
        if (m < nm) {
            float sc = red[0][m] + red[1][m] + red[2][m] + red[3][m] + b2[0];
            out[s_e[m]] = s_pv[m] * sc;
        }
    }
}

// ---------------------------------------------------------------------------
// Phase 3: aux loss
// ---------------------------------------------------------------------------
__global__ void aux_kernel(const float* __restrict__ probsum, float* __restrict__ out)
{
    if (threadIdx.x == 0 && blockIdx.x == 0) {
        float a = 0.0f;
        #pragma unroll
        for (int k = 0; k < 4; ++k) {
            float mean = probsum[k] * (1.0f / (float)E_EDGES);
            a += mean * mean;
        }
        out[E_EDGES] = a * (float)NEXP;
    }
}

extern "C" void kernel_launch(void* const* d_in, const int* in_sizes, int n_in,
                              void* d_out, int out_size, void* d_ws, size_t ws_size,
                              hipStream_t stream)
{
    const float* z   = (const float*)d_in[0];
    const int*   u   = (const int*)d_in[1];
    const int*   v   = (const int*)d_in[2];
    const float* gw  = (const float*)d_in[3];
    const float* gb  = (const float*)d_in[4];
    const float* cw1 = (const float*)d_in[5];
    const float* cb1 = (const float*)d_in[6];
    const float* cw2 = (const float*)d_in[7];
    const float* cb2 = (const float*)d_in[8];
    const float* dw1 = (const float*)d_in[9];
    const float* db1 = (const float*)d_in[10];
    const float* dw2 = (const float*)d_in[11];
    const float* db2 = (const float*)d_in[12];
    const float* mw1 = (const float*)d_in[13];
    const float* mb1 = (const float*)d_in[14];
    const float* mw2 = (const float*)d_in[15];
    const float* mb2 = (const float*)d_in[16];
    const float* aw1 = (const float*)d_in[17];
    const float* ab1 = (const float*)d_in[18];
    const float* aw2 = (const float*)d_in[19];
    const float* ab2 = (const float*)d_in[20];

    float* out = (float*)d_out;
    char*  ws  = (char*)d_ws;

    float*          probsum = (float*)ws;
    unsigned*       gcount  = (unsigned*)(ws + 16);
    int*            lists   = (int*)(ws + 32);
    float*          pval    = (float*)(ws + 32 + 16ll * E_EDGES);
    unsigned short* w1b     = (unsigned short*)(ws + 32 + 20ll * E_EDGES);

    hipMemsetAsync(d_ws, 0, 32, stream);

    conv_kernel<<<1024, 256, 0, stream>>>(cw1, dw1, mw1, aw1, w1b);

    gate_kernel<<<E_EDGES / 256, 256, 0, stream>>>(z, u, v, gw, gb,
                                                   probsum, gcount, lists, pval);

    aux_kernel<<<1, 64, 0, stream>>>(probsum, out);

    dim3 g2(E_EDGES / 32, 4);
    expert_kernel<<<g2, 256, 0, stream>>>(z, u, v, w1b,
                                          cb1, cw2, cb2,
                                          db1, dw2, db2,
                                          mb1, mw2, mb2,
                                          ab1, aw2, ab2,
                                          gcount, lists, pval, out);
}